// Round 7
// baseline (240.852 us; speedup 1.0000x reference)
//
#include <hip/hip_runtime.h>
#include <hip/hip_cooperative_groups.h>
#include <math.h>

namespace cg = cooperative_groups;

#define B_ 2
#define T_ 2048
#define D_ 512
#define H_ 8
#define HD_ 64
#define NG_ (B_*H_)
#define EPS_ 1e-5f

typedef __attribute__((ext_vector_type(8)))  short  short8;   // 8 bf16 (4 VGPRs)
typedef __attribute__((ext_vector_type(16))) float  floatx16; // MFMA 32x32 acc

__device__ inline floatx16 zero16() {
    floatx16 z;
#pragma unroll
    for (int i = 0; i < 16; i++) z[i] = 0.f;
    return z;
}

// round-to-nearest-even fp32 -> bf16
__device__ inline unsigned pack2bf(float a, float b) {
    unsigned ua = __float_as_uint(a), ub = __float_as_uint(b);
    ua = (ua + 0x7fffu + ((ua >> 16) & 1u)) >> 16;
    ub = (ub + 0x7fffu + ((ub >> 16) & 1u)) >> 16;
    return ua | (ub << 16);
}
__device__ inline short bf1(float a) {
    unsigned ua = __float_as_uint(a);
    return (short)((ua + 0x7fffu + ((ua >> 16) & 1u)) >> 16);
}

// =============== ONE cooperative kernel: convert -> proj -> retention -> norm
// 48 KB LDS byte-union: proj uses [2]x(8K X + 16K W) dbuf; retention 24 KB red.
__global__ __launch_bounds__(256, 2) void mega_kernel(
    const float* __restrict__ x,
    const float* __restrict__ Wq, const float* __restrict__ bq,
    const float* __restrict__ Wk, const float* __restrict__ bk,
    const float* __restrict__ Wv, const float* __restrict__ bv,
    const float* __restrict__ gn_w, const float* __restrict__ gn_b,
    const float* __restrict__ gamma_p,
    float* __restrict__ out, float* __restrict__ stats,
    short* __restrict__ xb, short* __restrict__ Wb,
    short* __restrict__ Qo, short* __restrict__ Ko, short* __restrict__ Vto,
    int G)
{
    cg::grid_group grid = cg::this_grid();
    __shared__ __align__(16) char smem[49152];

    const int tid = threadIdx.x;
    const int bid = blockIdx.x;
    const int gsz = G * 256;
    const int w = tid >> 6, lane = tid & 63;
    const int hi = lane >> 5, ln = lane & 31;

    // ---------------- phase 1: fp32->bf16 convert + zero stats --------------
    if (bid == 0 && tid < 32) stats[tid] = 0.f;
    {
        const int XN = 4096 * 512, WN = 512 * 512;
        const int TOT8 = (XN + 3 * WN) / 8;          // 360448 vec8 jobs
        for (int e8 = bid * 256 + tid; e8 < TOT8; e8 += gsz) {
            size_t e = (size_t)e8 * 8;
            const float* src; short* dst;
            if (e < XN)                 { src = x  + e;                 dst = xb + e; }
            else if (e < XN + WN)       { src = Wq + (e - XN);          dst = Wb + (e - XN); }
            else if (e < XN + 2u*WN)    { src = Wk + (e - XN - WN);     dst = Wb + (e - XN); }
            else                        { src = Wv + (e - XN - 2*WN);   dst = Wb + (e - XN); }
            float4 a = *(const float4*)src;
            float4 b = *(const float4*)(src + 4);
            uint4 o;
            o.x = pack2bf(a.x, a.y); o.y = pack2bf(a.z, a.w);
            o.z = pack2bf(b.x, b.y); o.w = pack2bf(b.z, b.w);
            *(uint4*)dst = o;
        }
    }
    grid.sync();

    // ---------------- phase 2: QKV projection (MFMA bf16, dbuf LDS) ---------
    {
        short* XsB = (short*)smem;            // [2][64*64]   (4096 shorts/buf)
        short* WsB = (short*)(smem + 16384);  // [2][128*64]  (8192 shorts/buf)
        const int srow = tid >> 3, scol = (tid & 7) * 8;
        const int mh = w & 1, nh = w >> 1;

        for (int job = bid; job < 768; job += G) {
            const int bx = job & 63, by = (job >> 6) & 3, z = job >> 8;
            const int mt0 = bx * 64, nt0 = by * 128;
            const bool isV = (z == 2);
            const float* bias = (z == 0) ? bq : (z == 1) ? bk : bv;
            const short* Wz = Wb + (size_t)z * 512 * 512;

            __syncthreads();   // previous job's LDS reads complete

            floatx16 acc[2] = {zero16(), zero16()};

            auto stage = [&](int b, int k0) {
#pragma unroll
                for (int i = 0; i < 2; i++) {
                    const short* gx = xb + (size_t)(mt0 + srow + i * 32) * 512 + k0 + scol;
                    short* lx = XsB + b * 4096 + (srow + i * 32) * 64 + scol;
                    __builtin_amdgcn_global_load_lds(
                        (const __attribute__((address_space(1))) unsigned*)gx,
                        (__attribute__((address_space(3))) unsigned*)lx, 16, 0, 0);
                }
#pragma unroll
                for (int i = 0; i < 4; i++) {
                    const short* gw = Wz + (size_t)(nt0 + srow + i * 32) * 512 + k0 + scol;
                    short* lw = WsB + b * 8192 + (srow + i * 32) * 64 + scol;
                    __builtin_amdgcn_global_load_lds(
                        (const __attribute__((address_space(1))) unsigned*)gw,
                        (__attribute__((address_space(3))) unsigned*)lw, 16, 0, 0);
                }
            };

            stage(0, 0);
            int buf = 0;
            for (int k0 = 0; k0 < 512; k0 += 64, buf ^= 1) {
                __syncthreads();                            // buf ready
                if (k0 + 64 < 512) stage(buf ^ 1, k0 + 64); // fill other buf
#pragma unroll
                for (int kk = 0; kk < 4; kk++) {
                    short8 xf = *(const short8*)(XsB + buf * 4096 + (mh * 32 + ln) * 64 + kk * 16 + hi * 8);
                    short8 wf[2];
#pragma unroll
                    for (int s = 0; s < 2; s++)
                        wf[s] = *(const short8*)(WsB + buf * 8192 + (nh * 64 + s * 32 + ln) * 64 + kk * 16 + hi * 8);
#pragma unroll
                    for (int b = 0; b < 2; b++)
                        acc[b] = isV
                            ? __builtin_amdgcn_mfma_f32_32x32x16_bf16(wf[b], xf, acc[b], 0, 0, 0)
                            : __builtin_amdgcn_mfma_f32_32x32x16_bf16(xf, wf[b], acc[b], 0, 0, 0);
                }
            }

            const int head = by * 2 + nh;
            if (!isV) {
                short* dst = (z == 0) ? Qo : Ko;
                float bias_v[2];
#pragma unroll
                for (int b = 0; b < 2; b++) bias_v[b] = bias[nt0 + nh * 64 + b * 32 + ln];
#pragma unroll
                for (int r = 0; r < 16; r++) {
                    int m = mt0 + mh * 32 + (r & 3) + 8 * (r >> 2) + 4 * hi;
                    int batch = m >> 11, t = m & (T_ - 1);
                    size_t rowb = ((size_t)(batch * H_ + head) * T_ + t) * HD_;
#pragma unroll
                    for (int b = 0; b < 2; b++)
                        dst[rowb + b * 32 + ln] = bf1(acc[b][r] + bias_v[b]);
                }
            } else {
                const int m = mt0 + mh * 32 + ln;
                const int batch = m >> 11, t = m & (T_ - 1);
#pragma unroll
                for (int b = 0; b < 2; b++) {
#pragma unroll
                    for (int r = 0; r < 16; r++) {
                        int chan = nt0 + nh * 64 + b * 32 + (r & 3) + 8 * (r >> 2) + 4 * hi;
                        int d = chan & (HD_ - 1);
                        Vto[((size_t)(batch * H_ + head) * HD_ + d) * T_ + t] = bf1(acc[b][r] + bias[chan]);
                    }
                }
            }
        }
    }
    grid.sync();

    // ---------------- phase 3: windowed retention (MFMA bf16) ---------------
    {
        float* red = (float*)smem;   // [3][32*64] = 24 KB
        const float gamma = gamma_p[0];
        const float lg = logf(gamma);
        const float Alane = __expf(lg * (float)(ln - 4 * hi));
        const float G32   = __expf(-lg * 32.0f);
        float Ea[4], Eb[4];
#pragma unroll
        for (int j = 0; j < 4; j++) { Ea[j] = __expf(-lg * (float)j); Eb[j] = __expf(-lg * (float)(8 * j)); }

        int ktw = 0;   // window size in 64-ktiles
        if (lg < -1e-6f) ktw = ((int)(-34.0f / lg) + 64) >> 6;

        for (int job = bid; job < 1024; job += G) {
            const int g = job & 15, qtt = job >> 4;
            const int q0 = qtt * 32;
            const int qt = qtt >> 1;
            const int ks = w;
            int kt0 = qt - ktw; if (kt0 < 0) kt0 = 0;
            const int qrel = (qtt & 1) * 32 + ln;

            __syncthreads();   // previous job's red reads complete

            const short* Qbase = Qo + ((size_t)g * T_ + q0 + ln) * HD_;
            short8 qf[4];
#pragma unroll
            for (int c = 0; c < 4; c++) qf[c] = *(const short8*)(Qbase + 16 * c + 8 * hi);

            floatx16 oacc[2] = {zero16(), zero16()};

            int kt = kt0 + ((ks - kt0) & 3);
            short8 kf[2][4];
            if (kt <= qt) {
                const short* Kbase = Ko + ((size_t)g * T_ + kt * 64) * HD_;
#pragma unroll
                for (int kh = 0; kh < 2; kh++)
#pragma unroll
                    for (int c = 0; c < 4; c++)
                        kf[kh][c] = *(const short8*)(Kbase + (size_t)(kh * 32 + ln) * HD_ + 16 * c + 8 * hi);
            }

            for (; kt <= qt; kt += 4) {
                const int k0 = kt * 64;

                floatx16 st[2];
#pragma unroll
                for (int kh = 0; kh < 2; kh++) {
                    floatx16 acc = zero16();
#pragma unroll
                    for (int c = 0; c < 4; c++)
                        acc = __builtin_amdgcn_mfma_f32_32x32x16_bf16(kf[kh][c], qf[c], acc, 0, 0, 0);
                    st[kh] = acc;
                }

                short8 vf[4][2];
#pragma unroll
                for (int c = 0; c < 4; c++)
#pragma unroll
                    for (int dh = 0; dh < 2; dh++)
                        vf[c][dh] = *(const short8*)(Vto + ((size_t)g * HD_ + dh * 32 + ln) * T_ + k0 + 16 * c + 8 * hi);

                const int ktn = kt + 4;
                if (ktn <= qt) {
                    const short* Kn = Ko + ((size_t)g * T_ + ktn * 64) * HD_;
#pragma unroll
                    for (int kh = 0; kh < 2; kh++)
#pragma unroll
                        for (int c = 0; c < 4; c++)
                            kf[kh][c] = *(const short8*)(Kn + (size_t)(kh * 32 + ln) * HD_ + 16 * c + 8 * hi);
                }

                const float Ckt = __expf(lg * (float)(q0 - k0));
                const float base0 = Alane * Ckt;
                const bool diag = (kt == qt);
#pragma unroll
                for (int kh = 0; kh < 2; kh++) {
                    float bb = base0 * (kh ? G32 : 1.0f);
#pragma unroll
                    for (int r = 0; r < 16; r++) {
                        float v = st[kh][r] * (bb * Ea[r & 3] * Eb[r >> 2]);
                        if (diag) {
                            int kloc = kh * 32 + (r & 3) + 8 * (r >> 2) + 4 * hi;
                            if (qrel < kloc) v = 0.f;
                        }
                        st[kh][r] = v;
                    }
                }

#pragma unroll
                for (int c = 0; c < 4; c++) {
                    const int kh = c >> 1, rb = 8 * (c & 1);
                    unsigned p0 = pack2bf(st[kh][rb+0], st[kh][rb+1]);
                    unsigned p1 = pack2bf(st[kh][rb+2], st[kh][rb+3]);
                    unsigned p2 = pack2bf(st[kh][rb+4], st[kh][rb+5]);
                    unsigned p3 = pack2bf(st[kh][rb+6], st[kh][rb+7]);
                    unsigned t0s = (unsigned)__shfl_xor((int)(hi ? p0 : p2), 32, 64);
                    unsigned t1s = (unsigned)__shfl_xor((int)(hi ? p1 : p3), 32, 64);
                    uint4 aw;
                    aw.x = hi ? t0s : p0;  aw.y = hi ? t1s : p1;
                    aw.z = hi ? p2  : t0s; aw.w = hi ? p3  : t1s;
                    short8 afr = *reinterpret_cast<short8*>(&aw);
#pragma unroll
                    for (int dh = 0; dh < 2; dh++)
                        oacc[dh] = __builtin_amdgcn_mfma_f32_32x32x16_bf16(afr, vf[c][dh], oacc[dh], 0, 0, 0);
                }
            }

            if (ks) {
                float* rp = red + (ks - 1) * 2048;
#pragma unroll
                for (int dh = 0; dh < 2; dh++)
#pragma unroll
                    for (int r = 0; r < 16; r++) {
                        int qloc = (r & 3) + 8 * (r >> 2) + 4 * hi;
                        rp[qloc * 64 + dh * 32 + ln] = oacc[dh][r];
                    }
            }
            __syncthreads();
            if (ks == 0) {
                const int b = g >> 3, h = g & 7;
                float sm = 0.f, sq = 0.f;
#pragma unroll
                for (int dh = 0; dh < 2; dh++)
#pragma unroll
                    for (int r = 0; r < 16; r++) {
                        int qloc = (r & 3) + 8 * (r >> 2) + 4 * hi;
                        int col = qloc * 64 + dh * 32 + ln;
                        float v = oacc[dh][r] + red[col] + red[2048 + col] + red[4096 + col];
                        int q = q0 + qloc;
                        out[((size_t)(b * T_ + q)) * D_ + h * 64 + dh * 32 + ln] = v;
                        sm += v; sq += v * v;
                    }
                for (int off = 32; off > 0; off >>= 1) {
                    sm += __shfl_down(sm, off);
                    sq += __shfl_down(sq, off);
                }
                if (lane == 0) {
                    atomicAdd(&stats[g], sm);
                    atomicAdd(&stats[NG_ + g], sq);
                }
            }
        }
    }
    grid.sync();

    // ---------------- phase 4: GroupNorm epilogue (in place, float4) --------
    {
        const float invN = 1.f / (float)(T_ * HD_);
        for (int idx4 = bid * 256 + tid; idx4 < (B_ * T_ * D_) / 4; idx4 += gsz) {
            int base = idx4 * 4;
            int c0 = base & (D_ - 1);
            int b = base >> 20;
            int g = b * H_ + (c0 >> 6);
            float mean = stats[g] * invN;
            float var  = stats[NG_ + g] * invN - mean * mean;
            float inv  = rsqrtf(var + EPS_);
            float4 v = *(float4*)&out[base];
            float4 wv = *(const float4*)&gn_w[c0];
            float4 bvv = *(const float4*)&gn_b[c0];
            v.x = (v.x - mean) * inv * wv.x + bvv.x;
            v.y = (v.y - mean) * inv * wv.y + bvv.y;
            v.z = (v.z - mean) * inv * wv.z + bvv.z;
            v.w = (v.w - mean) * inv * wv.w + bvv.w;
            *(float4*)&out[base] = v;
        }
    }
}

extern "C" void kernel_launch(void* const* d_in, const int* in_sizes, int n_in,
                              void* d_out, int out_size, void* d_ws, size_t ws_size,
                              hipStream_t stream)
{
    const float* x    = (const float*)d_in[0];
    const float* Wq   = (const float*)d_in[1];
    const float* bq   = (const float*)d_in[2];
    const float* Wk   = (const float*)d_in[3];
    const float* bk   = (const float*)d_in[4];
    const float* Wv   = (const float*)d_in[5];
    const float* bv   = (const float*)d_in[6];
    const float* gn_w = (const float*)d_in[7];
    const float* gn_b = (const float*)d_in[8];
    const float* gam  = (const float*)d_in[9];
    float* out = (float*)d_out;

    const size_t per = (size_t)B_ * H_ * T_ * HD_;   // 2M elements
    float* stats = (float*)d_ws;
    short* Qw  = (short*)((char*)d_ws + 256);
    short* Kw  = Qw + per;
    short* Vtw = Kw + per;
    short* xb  = Vtw + per;
    short* Wb  = xb + per;                            // 3*512*512 shorts

    int maxB = 0;
    hipOccupancyMaxActiveBlocksPerMultiprocessor(&maxB, mega_kernel, 256, 0);
    int G = maxB * 256;            // 256 CUs on MI355X
    if (G > 512) G = 512;
    if (G < 256) G = 256;

    void* args[] = {(void*)&x, (void*)&Wq, (void*)&bq, (void*)&Wk, (void*)&bk,
                    (void*)&Wv, (void*)&bv, (void*)&gn_w, (void*)&gn_b, (void*)&gam,
                    (void*)&out, (void*)&stats, (void*)&xb, (void*)&Wb,
                    (void*)&Qw, (void*)&Kw, (void*)&Vtw, (void*)&G};
    hipLaunchCooperativeKernel((const void*)mega_kernel, dim3(G), dim3(256),
                               args, 0, stream);
}

// Round 8
// 131.987 us; speedup vs baseline: 1.8248x; 1.8248x over previous
//
#include <hip/hip_runtime.h>
#include <math.h>

#define B_ 2
#define T_ 2048
#define D_ 512
#define H_ 8
#define HD_ 64
#define NG_ (B_*H_)
#define EPS_ 1e-5f

typedef __attribute__((ext_vector_type(8)))  short  short8;   // 8 bf16 (4 VGPRs)
typedef __attribute__((ext_vector_type(16))) float  floatx16; // MFMA 32x32 acc

__device__ inline floatx16 zero16() {
    floatx16 z;
#pragma unroll
    for (int i = 0; i < 16; i++) z[i] = 0.f;
    return z;
}

// round-to-nearest-even fp32 -> bf16
__device__ inline unsigned pack2bf(float a, float b) {
    unsigned ua = __float_as_uint(a), ub = __float_as_uint(b);
    ua = (ua + 0x7fffu + ((ua >> 16) & 1u)) >> 16;
    ub = (ub + 0x7fffu + ((ub >> 16) & 1u)) >> 16;
    return ua | (ub << 16);
}
__device__ inline short bf1(float a) {
    unsigned ua = __float_as_uint(a);
    return (short)((ua + 0x7fffu + ((ua >> 16) & 1u)) >> 16);
}

// ---------------- Kernel 0: fp32 -> bf16 convert + stats zero ----------
__global__ __launch_bounds__(256) void convert_kernel(
    const float* __restrict__ x,
    const float* __restrict__ Wq, const float* __restrict__ Wk, const float* __restrict__ Wv,
    short* __restrict__ xb, short* __restrict__ Wb, float* __restrict__ stats)
{
    if (blockIdx.x == 0 && threadIdx.x < 32) stats[threadIdx.x] = 0.f;
    const int XN = 4096 * 512;       // 2M
    const int WN = 512 * 512;        // 256K
    size_t e = ((size_t)blockIdx.x * 256 + threadIdx.x) * 8;
    const float* src; short* dst;
    if (e < XN)               { src = x  + e;               dst = xb + e; }
    else if (e < XN + WN)     { src = Wq + (e - XN);        dst = Wb + (e - XN); }
    else if (e < XN + 2*WN)   { src = Wk + (e - XN - WN);   dst = Wb + (e - XN); }
    else                      { src = Wv + (e - XN - 2*WN); dst = Wb + (e - XN); }
    float4 a = *(const float4*)src;
    float4 b = *(const float4*)(src + 4);
    uint4 o;
    o.x = pack2bf(a.x, a.y); o.y = pack2bf(a.z, a.w);
    o.z = pack2bf(b.x, b.y); o.w = pack2bf(b.z, b.w);
    *(uint4*)dst = o;
}

// ---------------- Kernel 1: QKV projection via MFMA bf16, double-buffered --
// C = x @ W^T + b. 64x128 tile/block, 4 waves each 32m x 64n.
// LDS 2x24KB -> 3 blocks/CU; stage k+1 overlaps compute k (1 barrier/step).
// Q,K -> [g][t][64] (lane = channel); V -> Vt[g][d][2048] (lane = token).
__global__ __launch_bounds__(256) void proj_mfma(
    const short* __restrict__ xb, const short* __restrict__ Wb,
    const float* __restrict__ bq, const float* __restrict__ bk, const float* __restrict__ bv,
    short* __restrict__ Qo, short* __restrict__ Ko, short* __restrict__ Vto)
{
    __shared__ short Xs[2][64 * 64];    // [buf][token][k]  2x8 KB
    __shared__ short Ws2[2][128 * 64];  // [buf][chan][k]   2x16 KB

    const int tid = threadIdx.x;
    const int w = tid >> 6, lane = tid & 63;
    const int hi = lane >> 5, ln = lane & 31;
    const int mt0 = blockIdx.x * 64;
    const int nt0 = blockIdx.y * 128;
    const int z = blockIdx.z;
    const bool isV = (z == 2);
    const float* bias = (z == 0) ? bq : (z == 1) ? bk : bv;
    const short* Wz = Wb + (size_t)z * 512 * 512;

    const int srow = tid >> 3;       // 0..31
    const int scol = (tid & 7) * 8;  // shorts
    const int mh = w & 1, nh = w >> 1;

    floatx16 acc[2] = {zero16(), zero16()};

    auto stage = [&](int b, int k0) {
#pragma unroll
        for (int i = 0; i < 2; i++) {
            const short* gx = xb + (size_t)(mt0 + srow + i * 32) * 512 + k0 + scol;
            short* lx = &Xs[b][(srow + i * 32) * 64 + scol];
            __builtin_amdgcn_global_load_lds(
                (const __attribute__((address_space(1))) unsigned*)gx,
                (__attribute__((address_space(3))) unsigned*)lx, 16, 0, 0);
        }
#pragma unroll
        for (int i = 0; i < 4; i++) {
            const short* gw = Wz + (size_t)(nt0 + srow + i * 32) * 512 + k0 + scol;
            short* lw = &Ws2[b][(srow + i * 32) * 64 + scol];
            __builtin_amdgcn_global_load_lds(
                (const __attribute__((address_space(1))) unsigned*)gw,
                (__attribute__((address_space(3))) unsigned*)lw, 16, 0, 0);
        }
    };

    stage(0, 0);
    int buf = 0;
    for (int k0 = 0; k0 < 512; k0 += 64, buf ^= 1) {
        __syncthreads();                       // buf ready (barrier drains vmcnt)
        if (k0 + 64 < 512) stage(buf ^ 1, k0 + 64);   // async fill of other buf
#pragma unroll
        for (int kk = 0; kk < 4; kk++) {
            short8 xf = *(const short8*)(&Xs[buf][(mh * 32 + ln) * 64 + kk * 16 + hi * 8]);
            short8 wf[2];
#pragma unroll
            for (int s = 0; s < 2; s++)
                wf[s] = *(const short8*)(&Ws2[buf][(nh * 64 + s * 32 + ln) * 64 + kk * 16 + hi * 8]);
#pragma unroll
            for (int b = 0; b < 2; b++)
                acc[b] = isV
                    ? __builtin_amdgcn_mfma_f32_32x32x16_bf16(wf[b], xf, acc[b], 0, 0, 0)
                    : __builtin_amdgcn_mfma_f32_32x32x16_bf16(xf, wf[b], acc[b], 0, 0, 0);
        }
    }

    const int head = blockIdx.y * 2 + nh;

    if (!isV) {
        short* dst = (z == 0) ? Qo : Ko;
        float bias_v[2];
#pragma unroll
        for (int b = 0; b < 2; b++) bias_v[b] = bias[nt0 + nh * 64 + b * 32 + ln];
#pragma unroll
        for (int r = 0; r < 16; r++) {
            int m = mt0 + mh * 32 + (r & 3) + 8 * (r >> 2) + 4 * hi;
            int batch = m >> 11, t = m & (T_ - 1);
            size_t rowb = ((size_t)(batch * H_ + head) * T_ + t) * HD_;
#pragma unroll
            for (int b = 0; b < 2; b++)
                dst[rowb + b * 32 + ln] = bf1(acc[b][r] + bias_v[b]);
        }
    } else {
        const int m = mt0 + mh * 32 + ln;
        const int batch = m >> 11, t = m & (T_ - 1);
#pragma unroll
        for (int b = 0; b < 2; b++) {
#pragma unroll
            for (int r = 0; r < 16; r++) {
                int chan = nt0 + nh * 64 + b * 32 + (r & 3) + 8 * (r >> 2) + 4 * hi;
                int d = chan & (HD_ - 1);
                Vto[((size_t)(batch * H_ + head) * HD_ + d) * T_ + t] = bf1(acc[b][r] + bias[chan]);
            }
        }
    }
}

// ---------------- Kernel 2: windowed retention, MFMA bf16, XCD-pinned ------
// grid (16 groups, 64 q-tiles of 32): linear wg%8 = g%8 pins each group's
// K/Vt to one XCD's L2. 4 waves = k-parity 0..3; next-K prefetch in-loop.
// launch_bounds(256,3): 3 blocks/CU (12 waves) for latency hiding.
__global__ __launch_bounds__(256, 3) void retention_kernel(
    const short* __restrict__ Q, const short* __restrict__ K, const short* __restrict__ Vt,
    const float* __restrict__ gamma_p,
    float* __restrict__ out,     // [B,T,D] pre-norm fp32
    float* __restrict__ stats)   // [16 sums][16 sumsq]
{
    __shared__ float red[3][32 * 64];   // partials from waves 1..3, 24 KB

    const int tid  = threadIdx.x;
    const int ks   = tid >> 6, lane = tid & 63;
    const int hi   = lane >> 5, ln = lane & 31;
    const int g    = blockIdx.x, qtt = blockIdx.y;   // x=g -> XCD = g%8
    const int q0   = qtt * 32;          // global query base
    const int qt   = qtt >> 1;          // 64-wide ktile index containing q0

    const float gamma = gamma_p[0];
    const float lg = logf(gamma);
    int kt0 = 0;
    if (lg < -1e-6f) {
        int maxd = (int)(-34.0f / lg) + 64;   // gamma^maxd < ~2e-15
        kt0 = qt - (maxd >> 6);
        if (kt0 < 0) kt0 = 0;
    }

    // Q fragments (B-operand of S^T = K*Q^T): col q = ln
    const short* Qbase = Q + ((size_t)g * T_ + q0 + ln) * HD_;
    short8 qf[4];
#pragma unroll
    for (int c = 0; c < 4; c++) qf[c] = *(const short8*)(Qbase + 16 * c + 8 * hi);

    // decay: gamma^(q-k) = Alane * Ckt * G32^kh * Ea[r&3]*Eb[r>>2]
    const float Alane = __expf(lg * (float)(ln - 4 * hi));
    const float G32   = __expf(-lg * 32.0f);
    float Ea[4], Eb[4];
#pragma unroll
    for (int j = 0; j < 4; j++) { Ea[j] = __expf(-lg * (float)j); Eb[j] = __expf(-lg * (float)(8 * j)); }
    const int qrel = (qtt & 1) * 32 + ln;   // q within its 64-ktile

    floatx16 oacc[2] = {zero16(), zero16()};

    int kt = kt0 + ((ks - kt0) & 3);
    short8 kf[2][4];
    if (kt <= qt) {
        const short* Kbase = K + ((size_t)g * T_ + kt * 64) * HD_;
#pragma unroll
        for (int kh = 0; kh < 2; kh++)
#pragma unroll
            for (int c = 0; c < 4; c++)
                kf[kh][c] = *(const short8*)(Kbase + (size_t)(kh * 32 + ln) * HD_ + 16 * c + 8 * hi);
    }

    for (; kt <= qt; kt += 4) {
        const int k0 = kt * 64;

        // S^T quadrants from prefetched K: A = K rows, B = Q cols
        floatx16 st[2];
#pragma unroll
        for (int kh = 0; kh < 2; kh++) {
            floatx16 acc = zero16();
#pragma unroll
            for (int c = 0; c < 4; c++)
                acc = __builtin_amdgcn_mfma_f32_32x32x16_bf16(kf[kh][c], qf[c], acc, 0, 0, 0);
            st[kh] = acc;
        }

        // V fragments for this ktile (in flight during decay+pack)
        short8 vf[4][2];
#pragma unroll
        for (int c = 0; c < 4; c++)
#pragma unroll
            for (int dh = 0; dh < 2; dh++)
                vf[c][dh] = *(const short8*)(Vt + ((size_t)g * HD_ + dh * 32 + ln) * T_ + k0 + 16 * c + 8 * hi);

        // prefetch next ktile's K fragments (st already holds S)
        const int ktn = kt + 4;
        if (ktn <= qt) {
            const short* Kn = K + ((size_t)g * T_ + ktn * 64) * HD_;
#pragma unroll
            for (int kh = 0; kh < 2; kh++)
#pragma unroll
                for (int c = 0; c < 4; c++)
                    kf[kh][c] = *(const short8*)(Kn + (size_t)(kh * 32 + ln) * HD_ + 16 * c + 8 * hi);
        }

        const float Ckt = __expf(lg * (float)(q0 - k0));
        const float base0 = Alane * Ckt;
        const bool diag = (kt == qt);
#pragma unroll
        for (int kh = 0; kh < 2; kh++) {
            float bb = base0 * (kh ? G32 : 1.0f);
#pragma unroll
            for (int r = 0; r < 16; r++) {
                float v = st[kh][r] * (bb * Ea[r & 3] * Eb[r >> 2]);
                if (diag) {
                    int kloc = kh * 32 + (r & 3) + 8 * (r >> 2) + 4 * hi;
                    if (qrel < kloc) v = 0.f;
                }
                st[kh][r] = v;
            }
        }

        // PV: O[q][d] += S[q][k] * V[k][d]
#pragma unroll
        for (int c = 0; c < 4; c++) {
            const int kh = c >> 1, rb = 8 * (c & 1);
            unsigned p0 = pack2bf(st[kh][rb+0], st[kh][rb+1]);
            unsigned p1 = pack2bf(st[kh][rb+2], st[kh][rb+3]);
            unsigned p2 = pack2bf(st[kh][rb+4], st[kh][rb+5]);
            unsigned p3 = pack2bf(st[kh][rb+6], st[kh][rb+7]);
            unsigned t0s = (unsigned)__shfl_xor((int)(hi ? p0 : p2), 32, 64);
            unsigned t1s = (unsigned)__shfl_xor((int)(hi ? p1 : p3), 32, 64);
            uint4 aw;
            aw.x = hi ? t0s : p0;  aw.y = hi ? t1s : p1;
            aw.z = hi ? p2  : t0s; aw.w = hi ? p3  : t1s;
            short8 afr = *reinterpret_cast<short8*>(&aw);
#pragma unroll
            for (int dh = 0; dh < 2; dh++)
                oacc[dh] = __builtin_amdgcn_mfma_f32_32x32x16_bf16(afr, vf[c][dh], oacc[dh], 0, 0, 0);
        }
    }

    // 4-way reduction via LDS
    if (ks) {
        float* rp = &red[ks - 1][0];
#pragma unroll
        for (int dh = 0; dh < 2; dh++)
#pragma unroll
            for (int r = 0; r < 16; r++) {
                int qloc = (r & 3) + 8 * (r >> 2) + 4 * hi;
                rp[qloc * 64 + dh * 32 + ln] = oacc[dh][r];
            }
    }
    __syncthreads();
    if (ks == 0) {
        const int b = g >> 3, h = g & 7;
        float sm = 0.f, sq = 0.f;
#pragma unroll
        for (int dh = 0; dh < 2; dh++)
#pragma unroll
            for (int r = 0; r < 16; r++) {
                int qloc = (r & 3) + 8 * (r >> 2) + 4 * hi;
                int col = qloc * 64 + dh * 32 + ln;
                float v = oacc[dh][r] + red[0][col] + red[1][col] + red[2][col];
                int q = q0 + qloc;
                out[((size_t)(b * T_ + q)) * D_ + h * 64 + dh * 32 + ln] = v;
                sm += v; sq += v * v;
            }
        for (int off = 32; off > 0; off >>= 1) {
            sm += __shfl_down(sm, off);
            sq += __shfl_down(sq, off);
        }
        if (lane == 0) {
            atomicAdd(&stats[g], sm);
            atomicAdd(&stats[NG_ + g], sq);
        }
    }
}

// ---------------- Kernel 3: GroupNorm epilogue (in place, float4) ----------
__global__ __launch_bounds__(256) void norm_kernel(
    float* __restrict__ out, const float* __restrict__ stats,
    const float* __restrict__ gn_w, const float* __restrict__ gn_b)
{
    int idx4 = blockIdx.x * 256 + threadIdx.x;
    if (idx4 >= (B_ * T_ * D_) / 4) return;
    int base = idx4 * 4;
    int c0 = base & (D_ - 1);
    int b = base >> 20;                 // T_*D_ = 2^20
    int g = b * H_ + (c0 >> 6);
    const float invN = 1.f / (float)(T_ * HD_);
    float mean = stats[g] * invN;
    float var  = stats[NG_ + g] * invN - mean * mean;
    float inv  = rsqrtf(var + EPS_);
    float4 v = *(float4*)&out[base];
    float4 wv = *(const float4*)&gn_w[c0];
    float4 bv = *(const float4*)&gn_b[c0];
    v.x = (v.x - mean) * inv * wv.x + bv.x;
    v.y = (v.y - mean) * inv * wv.y + bv.y;
    v.z = (v.z - mean) * inv * wv.z + bv.z;
    v.w = (v.w - mean) * inv * wv.w + bv.w;
    *(float4*)&out[base] = v;
}

extern "C" void kernel_launch(void* const* d_in, const int* in_sizes, int n_in,
                              void* d_out, int out_size, void* d_ws, size_t ws_size,
                              hipStream_t stream)
{
    const float* x    = (const float*)d_in[0];
    const float* Wq   = (const float*)d_in[1];
    const float* bq   = (const float*)d_in[2];
    const float* Wk   = (const float*)d_in[3];
    const float* bk   = (const float*)d_in[4];
    const float* Wv   = (const float*)d_in[5];
    const float* bv   = (const float*)d_in[6];
    const float* gn_w = (const float*)d_in[7];
    const float* gn_b = (const float*)d_in[8];
    const float* gam  = (const float*)d_in[9];
    float* out = (float*)d_out;

    const size_t per = (size_t)B_ * H_ * T_ * HD_;   // 2M elements
    float* stats = (float*)d_ws;
    short* Qw  = (short*)((char*)d_ws + 256);
    short* Kw  = Qw + per;
    short* Vtw = Kw + per;
    short* xb  = Vtw + per;
    short* Wb  = xb + per;                            // 3*512*512 shorts

    convert_kernel<<<1408, 256, 0, stream>>>(x, Wq, Wk, Wv, xb, Wb, stats);
    proj_mfma<<<dim3(64, 4, 3), 256, 0, stream>>>(xb, Wb, bq, bk, bv, Qw, Kw, Vtw);
    retention_kernel<<<dim3(16, 64), 256, 0, stream>>>(Qw, Kw, Vtw, gam, out, stats);
    norm_kernel<<<2048, 256, 0, stream>>>(out, stats, gn_w, gn_b);   // 2M/4/256
}

// Round 9
// 120.738 us; speedup vs baseline: 1.9948x; 1.0932x over previous
//
#include <hip/hip_runtime.h>
#include <math.h>

#define B_ 2
#define T_ 2048
#define D_ 512
#define H_ 8
#define HD_ 64
#define NG_ (B_*H_)
#define EPS_ 1e-5f

typedef __attribute__((ext_vector_type(8)))  short  short8;   // 8 bf16 (4 VGPRs)
typedef __attribute__((ext_vector_type(16))) float  floatx16; // MFMA 32x32 acc

__device__ inline floatx16 zero16() {
    floatx16 z;
#pragma unroll
    for (int i = 0; i < 16; i++) z[i] = 0.f;
    return z;
}

// round-to-nearest-even fp32 -> bf16
__device__ inline unsigned pack2bf(float a, float b) {
    unsigned ua = __float_as_uint(a), ub = __float_as_uint(b);
    ua = (ua + 0x7fffu + ((ua >> 16) & 1u)) >> 16;
    ub = (ub + 0x7fffu + ((ub >> 16) & 1u)) >> 16;
    return ua | (ub << 16);
}
__device__ inline short bf1(float a) {
    unsigned ua = __float_as_uint(a);
    return (short)((ua + 0x7fffu + ((ua >> 16) & 1u)) >> 16);
}

// ---------------- Kernel 0: fp32 -> bf16 convert + stats zero ----------
__global__ __launch_bounds__(256) void convert_kernel(
    const float* __restrict__ x,
    const float* __restrict__ Wq, const float* __restrict__ Wk, const float* __restrict__ Wv,
    short* __restrict__ xb, short* __restrict__ Wb, float* __restrict__ stats)
{
    if (blockIdx.x == 0 && threadIdx.x < 32) stats[threadIdx.x] = 0.f;
    const int XN = 4096 * 512;       // 2M
    const int WN = 512 * 512;        // 256K
    size_t e = ((size_t)blockIdx.x * 256 + threadIdx.x) * 8;
    const float* src; short* dst;
    if (e < XN)               { src = x  + e;               dst = xb + e; }
    else if (e < XN + WN)     { src = Wq + (e - XN);        dst = Wb + (e - XN); }
    else if (e < XN + 2*WN)   { src = Wk + (e - XN - WN);   dst = Wb + (e - XN); }
    else                      { src = Wv + (e - XN - 2*WN); dst = Wb + (e - XN); }
    float4 a = *(const float4*)src;
    float4 b = *(const float4*)(src + 4);
    uint4 o;
    o.x = pack2bf(a.x, a.y); o.y = pack2bf(a.z, a.w);
    o.z = pack2bf(b.x, b.y); o.w = pack2bf(b.z, b.w);
    *(uint4*)dst = o;
}

// ---------------- Kernel 1: QKV projection via MFMA bf16, dbuf + swizzle ---
// C = x @ W^T + b. 64x128 tile/block, 4 waves each 32m x 64n.
// LDS XOR-granule swizzle: row r's 16B granule s stored at slot s^(r&7) so
// ds_read_b128 lanes spread over all 8 bank-quads (was: 32 lanes on 1 quad).
__global__ __launch_bounds__(256) void proj_mfma(
    const short* __restrict__ xb, const short* __restrict__ Wb,
    const float* __restrict__ bq, const float* __restrict__ bk, const float* __restrict__ bv,
    short* __restrict__ Qo, short* __restrict__ Ko, short* __restrict__ Vto)
{
    __shared__ short Xs[2][64 * 64];    // [buf][token][k-swizzled]  2x8 KB
    __shared__ short Ws2[2][128 * 64];  // [buf][chan][k-swizzled]   2x16 KB

    const int tid = threadIdx.x;
    const int w = tid >> 6, lane = tid & 63;
    const int hi = lane >> 5, ln = lane & 31;
    const int mt0 = blockIdx.x * 64;
    const int nt0 = blockIdx.y * 128;
    const int z = blockIdx.z;
    const bool isV = (z == 2);
    const float* bias = (z == 0) ? bq : (z == 1) ? bk : bv;
    const short* Wz = Wb + (size_t)z * 512 * 512;

    const int srow = tid >> 3;                              // 0..31
    const int scol = (((tid & 7) ^ ((tid >> 3) & 7)) * 8);  // swizzled k-chunk
    const int mh = w & 1, nh = w >> 1;

    floatx16 acc[2] = {zero16(), zero16()};

    auto stage = [&](int b, int k0) {
#pragma unroll
        for (int i = 0; i < 2; i++) {
            const short* gx = xb + (size_t)(mt0 + srow + i * 32) * 512 + k0 + scol;
            short* lx = &Xs[b][(srow + i * 32) * 64 + (tid & 7) * 8];
            __builtin_amdgcn_global_load_lds(
                (const __attribute__((address_space(1))) unsigned*)gx,
                (__attribute__((address_space(3))) unsigned*)lx, 16, 0, 0);
        }
#pragma unroll
        for (int i = 0; i < 4; i++) {
            const short* gw = Wz + (size_t)(nt0 + srow + i * 32) * 512 + k0 + scol;
            short* lw = &Ws2[b][(srow + i * 32) * 64 + (tid & 7) * 8];
            __builtin_amdgcn_global_load_lds(
                (const __attribute__((address_space(1))) unsigned*)gw,
                (__attribute__((address_space(3))) unsigned*)lw, 16, 0, 0);
        }
    };

    stage(0, 0);
    int buf = 0;
    for (int k0 = 0; k0 < 512; k0 += 64, buf ^= 1) {
        __syncthreads();                       // buf ready (barrier drains vmcnt)
        if (k0 + 64 < 512) stage(buf ^ 1, k0 + 64);   // async fill of other buf
#pragma unroll
        for (int kk = 0; kk < 4; kk++) {
            const int gx = ((2 * kk + hi) ^ (ln & 7)) * 8;  // swizzled granule
            short8 xf = *(const short8*)(&Xs[buf][(mh * 32 + ln) * 64 + gx]);
            short8 wf[2];
#pragma unroll
            for (int s = 0; s < 2; s++)
                wf[s] = *(const short8*)(&Ws2[buf][(nh * 64 + s * 32 + ln) * 64 + gx]);
#pragma unroll
            for (int b = 0; b < 2; b++)
                acc[b] = isV
                    ? __builtin_amdgcn_mfma_f32_32x32x16_bf16(wf[b], xf, acc[b], 0, 0, 0)
                    : __builtin_amdgcn_mfma_f32_32x32x16_bf16(xf, wf[b], acc[b], 0, 0, 0);
        }
    }

    const int head = blockIdx.y * 2 + nh;

    if (!isV) {
        short* dst = (z == 0) ? Qo : Ko;
        float bias_v[2];
#pragma unroll
        for (int b = 0; b < 2; b++) bias_v[b] = bias[nt0 + nh * 64 + b * 32 + ln];
#pragma unroll
        for (int r = 0; r < 16; r++) {
            int m = mt0 + mh * 32 + (r & 3) + 8 * (r >> 2) + 4 * hi;
            int batch = m >> 11, t = m & (T_ - 1);
            size_t rowb = ((size_t)(batch * H_ + head) * T_ + t) * HD_;
#pragma unroll
            for (int b = 0; b < 2; b++)
                dst[rowb + b * 32 + ln] = bf1(acc[b][r] + bias_v[b]);
        }
    } else {
        const int m = mt0 + mh * 32 + ln;
        const int batch = m >> 11, t = m & (T_ - 1);
#pragma unroll
        for (int b = 0; b < 2; b++) {
#pragma unroll
            for (int r = 0; r < 16; r++) {
                int chan = nt0 + nh * 64 + b * 32 + (r & 3) + 8 * (r >> 2) + 4 * hi;
                int d = chan & (HD_ - 1);
                Vto[((size_t)(batch * H_ + head) * HD_ + d) * T_ + t] = bf1(acc[b][r] + bias[chan]);
            }
        }
    }
}

// ---------------- Kernel 2: windowed retention, MFMA bf16, XCD-pinned ------
// grid (16 groups, 64 q-tiles of 32): linear wg%8 = g%8 pins each group's
// K/Vt to one XCD's L2. 4 waves = k-parity 0..3; next-K prefetch in-loop.
// (256,2): VGPR cap 256 — live set ~175 regs, (256,3) spills to scratch.
__global__ __launch_bounds__(256, 2) void retention_kernel(
    const short* __restrict__ Q, const short* __restrict__ K, const short* __restrict__ Vt,
    const float* __restrict__ gamma_p,
    float* __restrict__ out,     // [B,T,D] pre-norm fp32
    float* __restrict__ stats)   // [16 sums][16 sumsq]
{
    __shared__ float red[3][32 * 64];   // partials from waves 1..3, 24 KB

    const int tid  = threadIdx.x;
    const int ks   = tid >> 6, lane = tid & 63;
    const int hi   = lane >> 5, ln = lane & 31;
    const int g    = blockIdx.x, qtt = blockIdx.y;   // x=g -> XCD = g%8
    const int q0   = qtt * 32;          // global query base
    const int qt   = qtt >> 1;          // 64-wide ktile index containing q0

    const float gamma = gamma_p[0];
    const float lg = logf(gamma);
    int kt0 = 0;
    if (lg < -1e-6f) {
        int maxd = (int)(-34.0f / lg) + 64;   // gamma^maxd < ~2e-15
        kt0 = qt - (maxd >> 6);
        if (kt0 < 0) kt0 = 0;
    }

    // Q fragments (B-operand of S^T = K*Q^T): col q = ln
    const short* Qbase = Q + ((size_t)g * T_ + q0 + ln) * HD_;
    short8 qf[4];
#pragma unroll
    for (int c = 0; c < 4; c++) qf[c] = *(const short8*)(Qbase + 16 * c + 8 * hi);

    // decay: gamma^(q-k) = Alane * Ckt * G32^kh * Ea[r&3]*Eb[r>>2]
    const float Alane = __expf(lg * (float)(ln - 4 * hi));
    const float G32   = __expf(-lg * 32.0f);
    float Ea[4], Eb[4];
#pragma unroll
    for (int j = 0; j < 4; j++) { Ea[j] = __expf(-lg * (float)j); Eb[j] = __expf(-lg * (float)(8 * j)); }
    const int qrel = (qtt & 1) * 32 + ln;   // q within its 64-ktile

    floatx16 oacc[2] = {zero16(), zero16()};

    int kt = kt0 + ((ks - kt0) & 3);
    short8 kf[2][4];
    if (kt <= qt) {
        const short* Kbase = K + ((size_t)g * T_ + kt * 64) * HD_;
#pragma unroll
        for (int kh = 0; kh < 2; kh++)
#pragma unroll
            for (int c = 0; c < 4; c++)
                kf[kh][c] = *(const short8*)(Kbase + (size_t)(kh * 32 + ln) * HD_ + 16 * c + 8 * hi);
    }

    for (; kt <= qt; kt += 4) {
        const int k0 = kt * 64;

        // S^T quadrants from prefetched K: A = K rows, B = Q cols
        floatx16 st[2];
#pragma unroll
        for (int kh = 0; kh < 2; kh++) {
            floatx16 acc = zero16();
#pragma unroll
            for (int c = 0; c < 4; c++)
                acc = __builtin_amdgcn_mfma_f32_32x32x16_bf16(kf[kh][c], qf[c], acc, 0, 0, 0);
            st[kh] = acc;
        }

        // V fragments for this ktile (in flight during decay+pack)
        short8 vf[4][2];
#pragma unroll
        for (int c = 0; c < 4; c++)
#pragma unroll
            for (int dh = 0; dh < 2; dh++)
                vf[c][dh] = *(const short8*)(Vt + ((size_t)g * HD_ + dh * 32 + ln) * T_ + k0 + 16 * c + 8 * hi);

        // prefetch next ktile's K fragments (st already holds S)
        const int ktn = kt + 4;
        if (ktn <= qt) {
            const short* Kn = K + ((size_t)g * T_ + ktn * 64) * HD_;
#pragma unroll
            for (int kh = 0; kh < 2; kh++)
#pragma unroll
                for (int c = 0; c < 4; c++)
                    kf[kh][c] = *(const short8*)(Kn + (size_t)(kh * 32 + ln) * HD_ + 16 * c + 8 * hi);
        }

        const float Ckt = __expf(lg * (float)(q0 - k0));
        const float base0 = Alane * Ckt;
        const bool diag = (kt == qt);
#pragma unroll
        for (int kh = 0; kh < 2; kh++) {
            float bb = base0 * (kh ? G32 : 1.0f);
#pragma unroll
            for (int r = 0; r < 16; r++) {
                float v = st[kh][r] * (bb * Ea[r & 3] * Eb[r >> 2]);
                if (diag) {
                    int kloc = kh * 32 + (r & 3) + 8 * (r >> 2) + 4 * hi;
                    if (qrel < kloc) v = 0.f;
                }
                st[kh][r] = v;
            }
        }

        // PV: O[q][d] += S[q][k] * V[k][d]
#pragma unroll
        for (int c = 0; c < 4; c++) {
            const int kh = c >> 1, rb = 8 * (c & 1);
            unsigned p0 = pack2bf(st[kh][rb+0], st[kh][rb+1]);
            unsigned p1 = pack2bf(st[kh][rb+2], st[kh][rb+3]);
            unsigned p2 = pack2bf(st[kh][rb+4], st[kh][rb+5]);
            unsigned p3 = pack2bf(st[kh][rb+6], st[kh][rb+7]);
            unsigned t0s = (unsigned)__shfl_xor((int)(hi ? p0 : p2), 32, 64);
            unsigned t1s = (unsigned)__shfl_xor((int)(hi ? p1 : p3), 32, 64);
            uint4 aw;
            aw.x = hi ? t0s : p0;  aw.y = hi ? t1s : p1;
            aw.z = hi ? p2  : t0s; aw.w = hi ? p3  : t1s;
            short8 afr = *reinterpret_cast<short8*>(&aw);
#pragma unroll
            for (int dh = 0; dh < 2; dh++)
                oacc[dh] = __builtin_amdgcn_mfma_f32_32x32x16_bf16(afr, vf[c][dh], oacc[dh], 0, 0, 0);
        }
    }

    // 4-way reduction via LDS
    if (ks) {
        float* rp = &red[ks - 1][0];
#pragma unroll
        for (int dh = 0; dh < 2; dh++)
#pragma unroll
            for (int r = 0; r < 16; r++) {
                int qloc = (r & 3) + 8 * (r >> 2) + 4 * hi;
                rp[qloc * 64 + dh * 32 + ln] = oacc[dh][r];
            }
    }
    __syncthreads();
    if (ks == 0) {
        const int b = g >> 3, h = g & 7;
        float sm = 0.f, sq = 0.f;
#pragma unroll
        for (int dh = 0; dh < 2; dh++)
#pragma unroll
            for (int r = 0; r < 16; r++) {
                int qloc = (r & 3) + 8 * (r >> 2) + 4 * hi;
                int col = qloc * 64 + dh * 32 + ln;
                float v = oacc[dh][r] + red[0][col] + red[1][col] + red[2][col];
                int q = q0 + qloc;
                out[((size_t)(b * T_ + q)) * D_ + h * 64 + dh * 32 + ln] = v;
                sm += v; sq += v * v;
            }
        for (int off = 32; off > 0; off >>= 1) {
            sm += __shfl_down(sm, off);
            sq += __shfl_down(sq, off);
        }
        if (lane == 0) {
            atomicAdd(&stats[g], sm);
            atomicAdd(&stats[NG_ + g], sq);
        }
    }
}

// ---------------- Kernel 3: GroupNorm epilogue (in place, float4) ----------
__global__ __launch_bounds__(256) void norm_kernel(
    float* __restrict__ out, const float* __restrict__ stats,
    const float* __restrict__ gn_w, const float* __restrict__ gn_b)
{
    int idx4 = blockIdx.x * 256 + threadIdx.x;
    if (idx4 >= (B_ * T_ * D_) / 4) return;
    int base = idx4 * 4;
    int c0 = base & (D_ - 1);
    int b = base >> 20;                 // T_*D_ = 2^20
    int g = b * H_ + (c0 >> 6);
    const float invN = 1.f / (float)(T_ * HD_);
    float mean = stats[g] * invN;
    float var  = stats[NG_ + g] * invN - mean * mean;
    float inv  = rsqrtf(var + EPS_);
    float4 v = *(float4*)&out[base];
    float4 wv = *(const float4*)&gn_w[c0];
    float4 bv = *(const float4*)&gn_b[c0];
    v.x = (v.x - mean) * inv * wv.x + bv.x;
    v.y = (v.y - mean) * inv * wv.y + bv.y;
    v.z = (v.z - mean) * inv * wv.z + bv.z;
    v.w = (v.w - mean) * inv * wv.w + bv.w;
    *(float4*)&out[base] = v;
}

extern "C" void kernel_launch(void* const* d_in, const int* in_sizes, int n_in,
                              void* d_out, int out_size, void* d_ws, size_t ws_size,
                              hipStream_t stream)
{
    const float* x    = (const float*)d_in[0];
    const float* Wq   = (const float*)d_in[1];
    const float* bq   = (const float*)d_in[2];
    const float* Wk   = (const float*)d_in[3];
    const float* bk   = (const float*)d_in[4];
    const float* Wv   = (const float*)d_in[5];
    const float* bv   = (const float*)d_in[6];
    const float* gn_w = (const float*)d_in[7];
    const float* gn_b = (const float*)d_in[8];
    const float* gam  = (const float*)d_in[9];
    float* out = (float*)d_out;

    const size_t per = (size_t)B_ * H_ * T_ * HD_;   // 2M elements
    float* stats = (float*)d_ws;
    short* Qw  = (short*)((char*)d_ws + 256);
    short* Kw  = Qw + per;
    short* Vtw = Kw + per;
    short* xb  = Vtw + per;
    short* Wb  = xb + per;                            // 3*512*512 shorts

    convert_kernel<<<1408, 256, 0, stream>>>(x, Wq, Wk, Wv, xb, Wb, stats);
    proj_mfma<<<dim3(64, 4, 3), 256, 0, stream>>>(xb, Wb, bq, bk, bv, Qw, Kw, Vtw);
    retention_kernel<<<dim3(16, 64), 256, 0, stream>>>(Qw, Kw, Vtw, gam, out, stats);
    norm_kernel<<<2048, 256, 0, stream>>>(out, stats, gn_w, gn_b);   // 2M/4/256
}

// Round 10
// 118.183 us; speedup vs baseline: 2.0380x; 1.0216x over previous
//
#include <hip/hip_runtime.h>
#include <math.h>

#define B_ 2
#define T_ 2048
#define D_ 512
#define H_ 8
#define HD_ 64
#define NG_ (B_*H_)
#define EPS_ 1e-5f

typedef __attribute__((ext_vector_type(8)))  short  short8;   // 8 bf16 (4 VGPRs)
typedef __attribute__((ext_vector_type(16))) float  floatx16; // MFMA 32x32 acc

__device__ inline floatx16 zero16() {
    floatx16 z;
#pragma unroll
    for (int i = 0; i < 16; i++) z[i] = 0.f;
    return z;
}

// round-to-nearest-even fp32 -> bf16
__device__ inline unsigned pack2bf(float a, float b) {
    unsigned ua = __float_as_uint(a), ub = __float_as_uint(b);
    ua = (ua + 0x7fffu + ((ua >> 16) & 1u)) >> 16;
    ub = (ub + 0x7fffu + ((ub >> 16) & 1u)) >> 16;
    return ua | (ub << 16);
}
__device__ inline short bf1(float a) {
    unsigned ua = __float_as_uint(a);
    return (short)((ua + 0x7fffu + ((ua >> 16) & 1u)) >> 16);
}

// ---------------- Kernel 0: fp32 -> bf16 convert + stats zero ----------
__global__ __launch_bounds__(256) void convert_kernel(
    const float* __restrict__ x,
    const float* __restrict__ Wq, const float* __restrict__ Wk, const float* __restrict__ Wv,
    short* __restrict__ xb, short* __restrict__ Wb, float* __restrict__ stats)
{
    if (blockIdx.x == 0 && threadIdx.x < 32) stats[threadIdx.x] = 0.f;
    const int XN = 4096 * 512;       // 2M
    const int WN = 512 * 512;        // 256K
    size_t e = ((size_t)blockIdx.x * 256 + threadIdx.x) * 8;
    const float* src; short* dst;
    if (e < XN)               { src = x  + e;               dst = xb + e; }
    else if (e < XN + WN)     { src = Wq + (e - XN);        dst = Wb + (e - XN); }
    else if (e < XN + 2*WN)   { src = Wk + (e - XN - WN);   dst = Wb + (e - XN); }
    else                      { src = Wv + (e - XN - 2*WN); dst = Wb + (e - XN); }
    float4 a = *(const float4*)src;
    float4 b = *(const float4*)(src + 4);
    uint4 o;
    o.x = pack2bf(a.x, a.y); o.y = pack2bf(a.z, a.w);
    o.z = pack2bf(b.x, b.y); o.w = pack2bf(b.z, b.w);
    *(uint4*)dst = o;
}

// ---------------- Kernel 1: QKV projection via MFMA bf16, dbuf + swizzle ---
// C = x @ W^T + b. 64x128 tile/block, 4 waves each 32m x 64n.
// LDS XOR-granule swizzle: row r's 16B granule s stored at slot s^(r&7).
// (256,3): 48KB LDS -> exactly 3 blocks/CU; grid 768 = one full round.
__global__ __launch_bounds__(256, 3) void proj_mfma(
    const short* __restrict__ xb, const short* __restrict__ Wb,
    const float* __restrict__ bq, const float* __restrict__ bk, const float* __restrict__ bv,
    short* __restrict__ Qo, short* __restrict__ Ko, short* __restrict__ Vto)
{
    __shared__ short Xs[2][64 * 64];    // [buf][token][k-swizzled]  2x8 KB
    __shared__ short Ws2[2][128 * 64];  // [buf][chan][k-swizzled]   2x16 KB

    const int tid = threadIdx.x;
    const int w = tid >> 6, lane = tid & 63;
    const int hi = lane >> 5, ln = lane & 31;
    const int mt0 = blockIdx.x * 64;
    const int nt0 = blockIdx.y * 128;
    const int z = blockIdx.z;
    const bool isV = (z == 2);
    const float* bias = (z == 0) ? bq : (z == 1) ? bk : bv;
    const short* Wz = Wb + (size_t)z * 512 * 512;

    const int srow = tid >> 3;                              // 0..31
    const int scol = (((tid & 7) ^ ((tid >> 3) & 7)) * 8);  // swizzled k-chunk
    const int mh = w & 1, nh = w >> 1;

    floatx16 acc[2] = {zero16(), zero16()};

    auto stage = [&](int b, int k0) {
#pragma unroll
        for (int i = 0; i < 2; i++) {
            const short* gx = xb + (size_t)(mt0 + srow + i * 32) * 512 + k0 + scol;
            short* lx = &Xs[b][(srow + i * 32) * 64 + (tid & 7) * 8];
            __builtin_amdgcn_global_load_lds(
                (const __attribute__((address_space(1))) unsigned*)gx,
                (__attribute__((address_space(3))) unsigned*)lx, 16, 0, 0);
        }
#pragma unroll
        for (int i = 0; i < 4; i++) {
            const short* gw = Wz + (size_t)(nt0 + srow + i * 32) * 512 + k0 + scol;
            short* lw = &Ws2[b][(srow + i * 32) * 64 + (tid & 7) * 8];
            __builtin_amdgcn_global_load_lds(
                (const __attribute__((address_space(1))) unsigned*)gw,
                (__attribute__((address_space(3))) unsigned*)lw, 16, 0, 0);
        }
    };

    stage(0, 0);
    int buf = 0;
    for (int k0 = 0; k0 < 512; k0 += 64, buf ^= 1) {
        __syncthreads();                       // buf ready (barrier drains vmcnt)
        if (k0 + 64 < 512) stage(buf ^ 1, k0 + 64);   // async fill of other buf
#pragma unroll
        for (int kk = 0; kk < 4; kk++) {
            const int gx = ((2 * kk + hi) ^ (ln & 7)) * 8;  // swizzled granule
            short8 xf = *(const short8*)(&Xs[buf][(mh * 32 + ln) * 64 + gx]);
            short8 wf[2];
#pragma unroll
            for (int s = 0; s < 2; s++)
                wf[s] = *(const short8*)(&Ws2[buf][(nh * 64 + s * 32 + ln) * 64 + gx]);
#pragma unroll
            for (int b = 0; b < 2; b++)
                acc[b] = isV
                    ? __builtin_amdgcn_mfma_f32_32x32x16_bf16(wf[b], xf, acc[b], 0, 0, 0)
                    : __builtin_amdgcn_mfma_f32_32x32x16_bf16(xf, wf[b], acc[b], 0, 0, 0);
        }
    }

    const int head = blockIdx.y * 2 + nh;

    if (!isV) {
        short* dst = (z == 0) ? Qo : Ko;
        float bias_v[2];
#pragma unroll
        for (int b = 0; b < 2; b++) bias_v[b] = bias[nt0 + nh * 64 + b * 32 + ln];
#pragma unroll
        for (int r = 0; r < 16; r++) {
            int m = mt0 + mh * 32 + (r & 3) + 8 * (r >> 2) + 4 * hi;
            int batch = m >> 11, t = m & (T_ - 1);
            size_t rowb = ((size_t)(batch * H_ + head) * T_ + t) * HD_;
#pragma unroll
            for (int b = 0; b < 2; b++)
                dst[rowb + b * 32 + ln] = bf1(acc[b][r] + bias_v[b]);
        }
    } else {
        const int m = mt0 + mh * 32 + ln;
        const int batch = m >> 11, t = m & (T_ - 1);
#pragma unroll
        for (int b = 0; b < 2; b++) {
#pragma unroll
            for (int r = 0; r < 16; r++) {
                int chan = nt0 + nh * 64 + b * 32 + (r & 3) + 8 * (r >> 2) + 4 * hi;
                int d = chan & (HD_ - 1);
                Vto[((size_t)(batch * H_ + head) * HD_ + d) * T_ + t] = bf1(acc[b][r] + bias[chan]);
            }
        }
    }
}

// ---------------- Kernel 2: windowed retention, MFMA bf16, XCD-pinned ------
// Window now sized for gamma^d < ~2e-6 (bf16-relevant precision): 3 ktiles
// at gamma=0.9 instead of 7 (-60% iterations). Tail error ~1e-6 << 0.0625.
// (256,2): live set ~175 VGPRs, (256,3) spills to scratch.
__global__ __launch_bounds__(256, 2) void retention_kernel(
    const short* __restrict__ Q, const short* __restrict__ K, const short* __restrict__ Vt,
    const float* __restrict__ gamma_p,
    float* __restrict__ out,     // [B,T,D] pre-norm fp32
    float* __restrict__ stats)   // [16 sums][16 sumsq]
{
    __shared__ float red[3][32 * 64];   // partials from waves 1..3, 24 KB

    const int tid  = threadIdx.x;
    const int ks   = tid >> 6, lane = tid & 63;
    const int hi   = lane >> 5, ln = lane & 31;
    const int g    = blockIdx.x, qtt = blockIdx.y;   // x=g -> XCD = g%8
    const int q0   = qtt * 32;          // global query base
    const int qt   = qtt >> 1;          // 64-wide ktile index containing q0

    const float gamma = gamma_p[0];
    const float lg = logf(gamma);
    int kt0 = 0;
    if (lg < -1e-6f) {
        int maxd = (int)(-13.0f / lg) + 64;   // gamma^maxd < ~2e-6 (+64 intra-tile pad)
        kt0 = qt - (maxd >> 6);
        if (kt0 < 0) kt0 = 0;
    }

    // Q fragments (B-operand of S^T = K*Q^T): col q = ln
    const short* Qbase = Q + ((size_t)g * T_ + q0 + ln) * HD_;
    short8 qf[4];
#pragma unroll
    for (int c = 0; c < 4; c++) qf[c] = *(const short8*)(Qbase + 16 * c + 8 * hi);

    // decay: gamma^(q-k) = Alane * Ckt * G32^kh * Ea[r&3]*Eb[r>>2]
    const float Alane = __expf(lg * (float)(ln - 4 * hi));
    const float G32   = __expf(-lg * 32.0f);
    float Ea[4], Eb[4];
#pragma unroll
    for (int j = 0; j < 4; j++) { Ea[j] = __expf(-lg * (float)j); Eb[j] = __expf(-lg * (float)(8 * j)); }
    const int qrel = (qtt & 1) * 32 + ln;   // q within its 64-ktile

    floatx16 oacc[2] = {zero16(), zero16()};

    int kt = kt0 + ((ks - kt0) & 3);
    short8 kf[2][4];
    if (kt <= qt) {
        const short* Kbase = K + ((size_t)g * T_ + kt * 64) * HD_;
#pragma unroll
        for (int kh = 0; kh < 2; kh++)
#pragma unroll
            for (int c = 0; c < 4; c++)
                kf[kh][c] = *(const short8*)(Kbase + (size_t)(kh * 32 + ln) * HD_ + 16 * c + 8 * hi);
    }

    for (; kt <= qt; kt += 4) {
        const int k0 = kt * 64;

        // S^T quadrants from prefetched K: A = K rows, B = Q cols
        floatx16 st[2];
#pragma unroll
        for (int kh = 0; kh < 2; kh++) {
            floatx16 acc = zero16();
#pragma unroll
            for (int c = 0; c < 4; c++)
                acc = __builtin_amdgcn_mfma_f32_32x32x16_bf16(kf[kh][c], qf[c], acc, 0, 0, 0);
            st[kh] = acc;
        }

        // V fragments for this ktile (in flight during decay+pack)
        short8 vf[4][2];
#pragma unroll
        for (int c = 0; c < 4; c++)
#pragma unroll
            for (int dh = 0; dh < 2; dh++)
                vf[c][dh] = *(const short8*)(Vt + ((size_t)g * HD_ + dh * 32 + ln) * T_ + k0 + 16 * c + 8 * hi);

        // prefetch next ktile's K fragments (st already holds S)
        const int ktn = kt + 4;
        if (ktn <= qt) {
            const short* Kn = K + ((size_t)g * T_ + ktn * 64) * HD_;
#pragma unroll
            for (int kh = 0; kh < 2; kh++)
#pragma unroll
                for (int c = 0; c < 4; c++)
                    kf[kh][c] = *(const short8*)(Kn + (size_t)(kh * 32 + ln) * HD_ + 16 * c + 8 * hi);
        }

        const float Ckt = __expf(lg * (float)(q0 - k0));
        const float base0 = Alane * Ckt;
        const bool diag = (kt == qt);
#pragma unroll
        for (int kh = 0; kh < 2; kh++) {
            float bb = base0 * (kh ? G32 : 1.0f);
#pragma unroll
            for (int r = 0; r < 16; r++) {
                float v = st[kh][r] * (bb * Ea[r & 3] * Eb[r >> 2]);
                if (diag) {
                    int kloc = kh * 32 + (r & 3) + 8 * (r >> 2) + 4 * hi;
                    if (qrel < kloc) v = 0.f;
                }
                st[kh][r] = v;
            }
        }

        // PV: O[q][d] += S[q][k] * V[k][d]
#pragma unroll
        for (int c = 0; c < 4; c++) {
            const int kh = c >> 1, rb = 8 * (c & 1);
            unsigned p0 = pack2bf(st[kh][rb+0], st[kh][rb+1]);
            unsigned p1 = pack2bf(st[kh][rb+2], st[kh][rb+3]);
            unsigned p2 = pack2bf(st[kh][rb+4], st[kh][rb+5]);
            unsigned p3 = pack2bf(st[kh][rb+6], st[kh][rb+7]);
            unsigned t0s = (unsigned)__shfl_xor((int)(hi ? p0 : p2), 32, 64);
            unsigned t1s = (unsigned)__shfl_xor((int)(hi ? p1 : p3), 32, 64);
            uint4 aw;
            aw.x = hi ? t0s : p0;  aw.y = hi ? t1s : p1;
            aw.z = hi ? p2  : t0s; aw.w = hi ? p3  : t1s;
            short8 afr = *reinterpret_cast<short8*>(&aw);
#pragma unroll
            for (int dh = 0; dh < 2; dh++)
                oacc[dh] = __builtin_amdgcn_mfma_f32_32x32x16_bf16(afr, vf[c][dh], oacc[dh], 0, 0, 0);
        }
    }

    // 4-way reduction via LDS
    if (ks) {
        float* rp = &red[ks - 1][0];
#pragma unroll
        for (int dh = 0; dh < 2; dh++)
#pragma unroll
            for (int r = 0; r < 16; r++) {
                int qloc = (r & 3) + 8 * (r >> 2) + 4 * hi;
                rp[qloc * 64 + dh * 32 + ln] = oacc[dh][r];
            }
    }
    __syncthreads();
    if (ks == 0) {
        const int b = g >> 3, h = g & 7;
        float sm = 0.f, sq = 0.f;
#pragma unroll
        for (int dh = 0; dh < 2; dh++)
#pragma unroll
            for (int r = 0; r < 16; r++) {
                int qloc = (r & 3) + 8 * (r >> 2) + 4 * hi;
                int col = qloc * 64 + dh * 32 + ln;
                float v = oacc[dh][r] + red[0][col] + red[1][col] + red[2][col];
                int q = q0 + qloc;
                out[((size_t)(b * T_ + q)) * D_ + h * 64 + dh * 32 + ln] = v;
                sm += v; sq += v * v;
            }
        for (int off = 32; off > 0; off >>= 1) {
            sm += __shfl_down(sm, off);
            sq += __shfl_down(sq, off);
        }
        if (lane == 0) {
            atomicAdd(&stats[g], sm);
            atomicAdd(&stats[NG_ + g], sq);
        }
    }
}

// ---------------- Kernel 3: GroupNorm epilogue (in place, float4) ----------
__global__ __launch_bounds__(256) void norm_kernel(
    float* __restrict__ out, const float* __restrict__ stats,
    const float* __restrict__ gn_w, const float* __restrict__ gn_b)
{
    int idx4 = blockIdx.x * 256 + threadIdx.x;
    if (idx4 >= (B_ * T_ * D_) / 4) return;
    int base = idx4 * 4;
    int c0 = base & (D_ - 1);
    int b = base >> 20;                 // T_*D_ = 2^20
    int g = b * H_ + (c0 >> 6);
    const float invN = 1.f / (float)(T_ * HD_);
    float mean = stats[g] * invN;
    float var  = stats[NG_ + g] * invN - mean * mean;
    float inv  = rsqrtf(var + EPS_);
    float4 v = *(float4*)&out[base];
    float4 wv = *(const float4*)&gn_w[c0];
    float4 bv = *(const float4*)&gn_b[c0];
    v.x = (v.x - mean) * inv * wv.x + bv.x;
    v.y = (v.y - mean) * inv * wv.y + bv.y;
    v.z = (v.z - mean) * inv * wv.z + bv.z;
    v.w = (v.w - mean) * inv * wv.w + bv.w;
    *(float4*)&out[base] = v;
}

extern "C" void kernel_launch(void* const* d_in, const int* in_sizes, int n_in,
                              void* d_out, int out_size, void* d_ws, size_t ws_size,
                              hipStream_t stream)
{
    const float* x    = (const float*)d_in[0];
    const float* Wq   = (const float*)d_in[1];
    const float* bq   = (const float*)d_in[2];
    const float* Wk   = (const float*)d_in[3];
    const float* bk   = (const float*)d_in[4];
    const float* Wv   = (const float*)d_in[5];
    const float* bv   = (const float*)d_in[6];
    const float* gn_w = (const float*)d_in[7];
    const float* gn_b = (const float*)d_in[8];
    const float* gam  = (const float*)d_in[9];
    float* out = (float*)d_out;

    const size_t per = (size_t)B_ * H_ * T_ * HD_;   // 2M elements
    float* stats = (float*)d_ws;
    short* Qw  = (short*)((char*)d_ws + 256);
    short* Kw  = Qw + per;
    short* Vtw = Kw + per;
    short* xb  = Vtw + per;
    short* Wb  = xb + per;                            // 3*512*512 shorts

    convert_kernel<<<1408, 256, 0, stream>>>(x, Wq, Wk, Wv, xb, Wb, stats);
    proj_mfma<<<dim3(64, 4, 3), 256, 0, stream>>>(xb, Wb, bq, bk, bv, Qw, Kw, Vtw);
    retention_kernel<<<dim3(16, 64), 256, 0, stream>>>(Qw, Kw, Vtw, gam, out, stats);
    norm_kernel<<<2048, 256, 0, stream>>>(out, stats, gn_w, gn_b);   // 2M/4/256
}